// Round 7
// baseline (750.635 us; speedup 1.0000x reference)
//
#include <hip/hip_runtime.h>
#include <stdint.h>

#define NN    50000
#define INC   128
#define HIDC  256
#define OUTC  40
#define GCH   128
#define NL    4
#define NG    2
#define NEDGE 600000
#define EPSV  1e-5f

typedef __bf16 bf16x8 __attribute__((ext_vector_type(8)));
typedef float  f32x4  __attribute__((ext_vector_type(4)));
typedef unsigned short u16x4 __attribute__((ext_vector_type(4)));
typedef unsigned short u16x8 __attribute__((ext_vector_type(8)));

__device__ __forceinline__ float bf2f(unsigned short u) {
    union { float f; unsigned int i; } v;
    v.i = ((unsigned int)u) << 16;
    return v.f;
}
__device__ __forceinline__ unsigned short f2bf(float f) {
    union { float f; unsigned int i; } v;
    v.f = f;
    unsigned int u = v.i;
    u += 0x7FFFu + ((u >> 16) & 1u);   // RNE
    return (unsigned short)(u >> 16);
}
__device__ __forceinline__ float ldf(const void* p, int is_f32, long long i) {
    if (is_f32) return ((const float*)p)[i];
    return bf2f(((const unsigned short*)p)[i]);
}
__device__ __forceinline__ bf16x8 ld8(const unsigned short* p) {
    return *(const bf16x8*)p;
}

// ---- diagnostic marker ----
__global__ void k_marker(void* out, float val, int n) {
    int i = blockIdx.x * 256 + threadIdx.x;
    if (i < n) ((unsigned short*)out)[i] = f2bf(val);
}

// ---- zero deg + detect dtypes (proven) ----
__global__ void k_detect(const int* ei, const unsigned short* xprobe,
                         int* flags, int* deg) {
    int t = threadIdx.x;
    int gid = blockIdx.x * 256 + t;
    if (gid < NN) deg[gid] = 0;
    if (blockIdx.x == 0) {
        __shared__ int hi_or;
        __shared__ int wild_cnt;
        if (t == 0) { hi_or = 0; wild_cnt = 0; }
        __syncthreads();
        int acc = 0;
        for (int i = 0; i < 8; i++) acc |= ei[2 * (t + i * 256) + 1];
        if (acc) atomicOr(&hi_or, 1);
        int wild = 0;
        for (int i = 0; i < 2; i++) {
            unsigned short u = xprobe[t + i * 256];
            int e = (u >> 7) & 0xFF;
            if (e <= 0x30 || e >= 0xC0) wild++;
        }
        atomicAdd(&wild_cnt, wild);
        __syncthreads();
        if (t == 0) {
            flags[0] = hi_or ? 0 : 1;           // 1 => int64 edge_index
            flags[1] = (wild_cnt > 32) ? 1 : 0; // 1 => fp32 float tensors
        }
    }
}

// ---- one-time convert ----
#define CVT_X   6400000
#define CVT_W1  32768
#define CVT_CW  131072
#define CVT_W2  12288
#define CVT_TOT (CVT_X + CVT_W1 + CVT_CW + CVT_W2)

__global__ void k_convert(const void* x, const void* w1, const void* cw, const void* w2,
                          const int* flags,
                          unsigned short* xb, unsigned short* w1t,
                          unsigned short* cwt, unsigned short* w2t) {
    long long idx = (long long)blockIdx.x * 256 + threadIdx.x;
    if (idx >= CVT_TOT) return;
    int f32 = flags[1];
    if (idx < CVT_X) {
        xb[idx] = f2bf(ldf(x, f32, idx));
    } else if (idx < CVT_X + CVT_W1) {
        long long j = idx - CVT_X;
        int n = (int)(j >> 7), k = (int)(j & 127);
        w1t[j] = f2bf(ldf(w1, f32, (long long)k * HIDC + n));
    } else if (idx < CVT_X + CVT_W1 + CVT_CW) {
        long long j = idx - (CVT_X + CVT_W1);
        int lg = (int)(j >> 14);
        int rem = (int)(j & 16383);
        int n = rem >> 7, k = rem & 127;
        cwt[j] = f2bf(ldf(cw, f32, (long long)lg * GCH * GCH + (long long)k * GCH + n));
    } else {
        long long j = idx - (CVT_X + CVT_W1 + CVT_CW);
        int n = (int)(j >> 8), k = (int)(j & 255);
        w2t[j] = (n < OUTC) ? f2bf(ldf(w2, f32, (long long)k * OUTC + n)) : (unsigned short)0;
    }
}

__global__ void k_convert2(const void* b1, const void* ng, const void* nb, const void* cb,
                           const void* fg, const void* fb, const void* b2,
                           const int* flags,
                           float* b1f, float* ngf, float* nbf, float* cbf,
                           float* fgf, float* fbf, float* b2f) {
    int t = threadIdx.x;
    int f32 = flags[1];
    b1f[t] = ldf(b1, f32, t);
    fgf[t] = ldf(fg, f32, t);
    fbf[t] = ldf(fb, f32, t);
    if (t < 48) b2f[t] = (t < OUTC) ? ldf(b2, f32, t) : 0.0f;
    for (int i = 0; i < 4; i++) {
        int j = t + i * 256;
        ngf[j] = ldf(ng, f32, j);
        nbf[j] = ldf(nb, f32, j);
        cbf[j] = ldf(cb, f32, j);
    }
}

// ---- lin1: h = xb @ W1 + b1 ----
__global__ __launch_bounds__(256) void k_lin1(
    const unsigned short* __restrict__ xb,
    const unsigned short* __restrict__ w1t,
    const float* __restrict__ b1f,
    float* __restrict__ h)
{
    int bx = blockIdx.x;
    int r0 = (bx >> 1) * 128;
    int n0 = (bx & 1) * 128;
    int w = threadIdx.x >> 6, lane = threadIdx.x & 63;
    int quad = lane >> 4, ln = lane & 15;
    const f32x4 zf = {0.f, 0.f, 0.f, 0.f};
    const bf16x8 zb = {0, 0, 0, 0, 0, 0, 0, 0};
    f32x4 acc[2][8];
#pragma unroll
    for (int i = 0; i < 2; i++)
#pragma unroll
        for (int j = 0; j < 8; j++) acc[i][j] = zf;

#pragma unroll
    for (int kk = 0; kk < 4; kk++) {
        int ko = kk * 32 + quad * 8;
        bf16x8 a0, a1;
        {
            int r = r0 + w * 32 + ln;
            a0 = (r < NN) ? ld8(xb + (long long)r * INC + ko) : zb;
            r += 16;
            a1 = (r < NN) ? ld8(xb + (long long)r * INC + ko) : zb;
        }
#pragma unroll
        for (int nf = 0; nf < 8; nf++) {
            bf16x8 b = ld8(w1t + (long long)(n0 + nf * 16 + ln) * INC + ko);
            acc[0][nf] = __builtin_amdgcn_mfma_f32_16x16x32_bf16(a0, b, acc[0][nf], 0, 0, 0);
            acc[1][nf] = __builtin_amdgcn_mfma_f32_16x16x32_bf16(a1, b, acc[1][nf], 0, 0, 0);
        }
    }
#pragma unroll
    for (int mi = 0; mi < 2; mi++)
#pragma unroll
        for (int nf = 0; nf < 8; nf++) {
            int col = n0 + nf * 16 + ln;
            float bias = b1f[col];
#pragma unroll
            for (int r4 = 0; r4 < 4; r4++) {
                int row = r0 + w * 32 + mi * 16 + quad * 4 + r4;
                if (row < NN) h[(long long)row * HIDC + col] = acc[mi][nf][r4] + bias;
            }
        }
}

// ---- standalone LN+ReLU+GEMM (only for block 0) ----
#define TSTR 152
__global__ __launch_bounds__(256) void k_ln_gemm(
    const float* __restrict__ h,
    const unsigned short* __restrict__ cw,
    const float* __restrict__ ga,
    const float* __restrict__ be,
    int in_half,
    unsigned short* __restrict__ z)
{
    __shared__ __align__(16) unsigned short a_tile[128 * TSTR];
    int t = threadIdx.x;
    int r0 = blockIdx.x * 128;

    int row = t >> 1, hh = t & 1;
    int r = r0 + row;
    const float* hp = h + (long long)r * HIDC + in_half * GCH + hh * 64;

    float sum = 0.f, sq = 0.f;
    float vbuf[64];
    if (r < NN) {
#pragma unroll
        for (int i = 0; i < 16; i++) {
            f32x4 v = *(const f32x4*)(hp + i * 4);
#pragma unroll
            for (int j = 0; j < 4; j++) {
                vbuf[i * 4 + j] = v[j];
                sum += v[j];
                sq += v[j] * v[j];
            }
        }
    } else {
#pragma unroll
        for (int i = 0; i < 64; i++) vbuf[i] = 0.f;
    }
    sum += __shfl_xor(sum, 1, 64);
    sq  += __shfl_xor(sq, 1, 64);
    float mu = sum * (1.0f / GCH);
    float var = sq * (1.0f / GCH) - mu * mu;
    float rs = rsqrtf(var + EPSV);

#pragma unroll
    for (int i = 0; i < 16; i++) {
        int c = hh * 64 + i * 4;
        u16x4 o;
#pragma unroll
        for (int j = 0; j < 4; j++) {
            float val = (vbuf[i * 4 + j] - mu) * rs * ga[c + j] + be[c + j];
            if (val < 0.f) val = 0.f;
            o[j] = f2bf(val);
        }
        *(u16x4*)(&a_tile[row * TSTR + c]) = o;
    }
    __syncthreads();

    int w = t >> 6, lane = t & 63;
    int quad = lane >> 4, ln = lane & 15;
    const f32x4 zf = {0.f, 0.f, 0.f, 0.f};
    f32x4 acc[2][8];
#pragma unroll
    for (int i = 0; i < 2; i++)
#pragma unroll
        for (int j = 0; j < 8; j++) acc[i][j] = zf;

#pragma unroll
    for (int kk = 0; kk < 4; kk++) {
        int ko = kk * 32 + quad * 8;
        bf16x8 a0 = *(const bf16x8*)(&a_tile[(w * 32 + ln) * TSTR + ko]);
        bf16x8 a1 = *(const bf16x8*)(&a_tile[(w * 32 + 16 + ln) * TSTR + ko]);
#pragma unroll
        for (int nf = 0; nf < 8; nf++) {
            bf16x8 b = ld8(cw + (long long)(nf * 16 + ln) * GCH + ko);
            acc[0][nf] = __builtin_amdgcn_mfma_f32_16x16x32_bf16(a0, b, acc[0][nf], 0, 0, 0);
            acc[1][nf] = __builtin_amdgcn_mfma_f32_16x16x32_bf16(a1, b, acc[1][nf], 0, 0, 0);
        }
    }
#pragma unroll
    for (int mi = 0; mi < 2; mi++)
#pragma unroll
        for (int nf = 0; nf < 8; nf++) {
            int col = nf * 16 + ln;
#pragma unroll
            for (int r4 = 0; r4 < 4; r4++) {
                int row2 = r0 + w * 32 + mi * 16 + quad * 4 + r4;
                if (row2 < NN) z[(long long)row2 * GCH + col] = f2bf(acc[mi][nf][r4]);
            }
        }
}

// ---- CSR build ----
__global__ void k_count(const int* __restrict__ ei, const int* __restrict__ flags,
                        int* __restrict__ deg) {
    int e = (blockIdx.x * 256 + threadIdx.x) * 2;
    if (e >= NEDGE) return;
    int d0, d1;
    if (flags[0]) {
        int4 v = *(const int4*)(ei + 2 * (NEDGE + e));
        d0 = v.x; d1 = v.z;
    } else {
        int2 v = *(const int2*)(ei + NEDGE + e);
        d0 = v.x; d1 = v.y;
    }
    atomicAdd(&deg[d0], 1);
    if (e + 1 < NEDGE) atomicAdd(&deg[d1], 1);
}

#define SCAN_B 49
__global__ void k_scan_a(const int* __restrict__ deg, int* __restrict__ bsum) {
    __shared__ int part[256];
    int b = blockIdx.x, t = threadIdx.x;
    int base = b * 1024 + t * 4;
    int s = 0;
#pragma unroll
    for (int j = 0; j < 4; j++) {
        int i = base + j;
        if (i < NN) s += deg[i];
    }
    part[t] = s;
    __syncthreads();
    for (int off = 128; off > 0; off >>= 1) {
        if (t < off) part[t] += part[t + off];
        __syncthreads();
    }
    if (t == 0) bsum[b] = part[0];
}

__global__ void k_scan_b(const int* __restrict__ bsum, int* __restrict__ boff) {
    if (threadIdx.x == 0) {
        int run = 0;
        for (int i = 0; i < SCAN_B; i++) { boff[i] = run; run += bsum[i]; }
    }
}

__global__ void k_scan_c(const int* __restrict__ deg, const int* __restrict__ boff,
                         int* __restrict__ rowptr, int* __restrict__ cursor) {
    __shared__ int part[256];
    int b = blockIdx.x, t = threadIdx.x;
    int base = b * 1024 + t * 4;
    int v[4];
    int s = 0;
#pragma unroll
    for (int j = 0; j < 4; j++) {
        int i = base + j;
        v[j] = (i < NN) ? deg[i] : 0;
        s += v[j];
    }
    part[t] = s;
    __syncthreads();
    for (int off = 1; off < 256; off <<= 1) {
        int x = (t >= off) ? part[t - off] : 0;
        __syncthreads();
        part[t] += x;
        __syncthreads();
    }
    int run = boff[b] + part[t] - s;
#pragma unroll
    for (int j = 0; j < 4; j++) {
        int i = base + j;
        if (i < NN) { rowptr[i] = run; cursor[i] = run; }
        run += v[j];
    }
    if (b == SCAN_B - 1 && t == 255) rowptr[NN] = NEDGE;
}

// R5-proven two-array fill + 2-edge batching (two atomics in flight)
__global__ void k_fill(const int* __restrict__ ei, const void* __restrict__ ew,
                       const int* __restrict__ flags,
                       int* __restrict__ cursor, int* __restrict__ ssrc,
                       float* __restrict__ sw) {
    int e = (blockIdx.x * 256 + threadIdx.x) * 2;
    if (e >= NEDGE) return;
    int is64 = flags[0];
    int f32 = flags[1];
    int d0, s0, d1 = 0, s1 = 0;
    int has1 = (e + 1 < NEDGE);
    if (is64) {
        d0 = ei[2 * (NEDGE + e)];
        s0 = ei[2 * e];
        if (has1) { d1 = ei[2 * (NEDGE + e) + 2]; s1 = ei[2 * e + 2]; }
    } else {
        d0 = ei[NEDGE + e];
        s0 = ei[e];
        if (has1) { d1 = ei[NEDGE + e + 1]; s1 = ei[e + 1]; }
    }
    int p0 = atomicAdd(&cursor[d0], 1);
    int p1 = has1 ? atomicAdd(&cursor[d1], 1) : 0;
    ssrc[p0] = s0;
    sw[p0] = ldf(ew, f32, e);
    if (has1) {
        ssrc[p1] = s1;
        sw[p1] = ldf(ew, f32, e + 1);
    }
}

// ---- FUSED: agg(lg) into h[half] + LN + ReLU + GEMM(next lg) -> zout ----
#define FTM 64
__global__ __launch_bounds__(256) void k_fused(
    float* __restrict__ h,
    const int* __restrict__ rowptr, const int* __restrict__ ssrc,
    const float* __restrict__ sw,
    const unsigned short* __restrict__ zin,
    const float* __restrict__ cb,            // conv bias of agg's lg
    const unsigned short* __restrict__ cw,   // conv weight of NEXT lg (transposed)
    const float* __restrict__ ga, const float* __restrict__ be, // LN of next lg
    int half,
    unsigned short* __restrict__ zout)
{
    __shared__ __align__(16) unsigned short a_tile[FTM * TSTR];
    int t = threadIdx.x;
    int r0 = blockIdx.x * FTM;
    int row = t >> 2, part = t & 3;
    int r = r0 + row;
    int c0 = part * 32;

    float acc[32];
#pragma unroll
    for (int i = 0; i < 32; i++) acc[i] = 0.f;

    if (r < NN) {
        int beg = rowptr[r], end = rowptr[r + 1];
        const unsigned short* zb = zin + c0;
        int e = beg;
        for (; e + 1 < end; e += 2) {
            int s0 = ssrc[e], s1 = ssrc[e + 1];
            float w0 = sw[e], w1 = sw[e + 1];
            const unsigned short* z0 = zb + (long long)s0 * GCH;
            const unsigned short* z1 = zb + (long long)s1 * GCH;
            u16x8 a0 = *(const u16x8*)(z0);      u16x8 a1 = *(const u16x8*)(z0 + 8);
            u16x8 a2 = *(const u16x8*)(z0 + 16); u16x8 a3 = *(const u16x8*)(z0 + 24);
            u16x8 b0 = *(const u16x8*)(z1);      u16x8 b1 = *(const u16x8*)(z1 + 8);
            u16x8 b2 = *(const u16x8*)(z1 + 16); u16x8 b3 = *(const u16x8*)(z1 + 24);
#pragma unroll
            for (int j = 0; j < 8; j++) {
                acc[j]      += w0 * bf2f(a0[j]) + w1 * bf2f(b0[j]);
                acc[8 + j]  += w0 * bf2f(a1[j]) + w1 * bf2f(b1[j]);
                acc[16 + j] += w0 * bf2f(a2[j]) + w1 * bf2f(b2[j]);
                acc[24 + j] += w0 * bf2f(a3[j]) + w1 * bf2f(b3[j]);
            }
        }
        if (e < end) {
            int s0 = ssrc[e];
            float w0 = sw[e];
            const unsigned short* z0 = zb + (long long)s0 * GCH;
            u16x8 a0 = *(const u16x8*)(z0);      u16x8 a1 = *(const u16x8*)(z0 + 8);
            u16x8 a2 = *(const u16x8*)(z0 + 16); u16x8 a3 = *(const u16x8*)(z0 + 24);
#pragma unroll
            for (int j = 0; j < 8; j++) {
                acc[j]      += w0 * bf2f(a0[j]);
                acc[8 + j]  += w0 * bf2f(a1[j]);
                acc[16 + j] += w0 * bf2f(a2[j]);
                acc[24 + j] += w0 * bf2f(a3[j]);
            }
        }
    }

    float sum = 0.f, sq = 0.f;
    if (r < NN) {
        float* hp = h + (long long)r * HIDC + half * GCH + c0;
#pragma unroll
        for (int i = 0; i < 8; i++) {
            f32x4 hv = *(const f32x4*)(hp + i * 4);
            f32x4 up;
#pragma unroll
            for (int j = 0; j < 4; j++) {
                float u = hv[j] + acc[i * 4 + j] + cb[c0 + i * 4 + j];
                up[j] = u;
                acc[i * 4 + j] = u;   // reuse acc as updated value
                sum += u;
                sq += u * u;
            }
            *(f32x4*)(hp + i * 4) = up;   // residual write-back
        }
    }
    sum += __shfl_xor(sum, 1, 64);
    sum += __shfl_xor(sum, 2, 64);
    sq  += __shfl_xor(sq, 1, 64);
    sq  += __shfl_xor(sq, 2, 64);
    float mu = sum * (1.0f / GCH);
    float var = sq * (1.0f / GCH) - mu * mu;
    float rs = rsqrtf(var + EPSV);

    if (r < NN) {
#pragma unroll
        for (int i = 0; i < 8; i++) {
            int c = c0 + i * 4;
            u16x4 o;
#pragma unroll
            for (int j = 0; j < 4; j++) {
                float val = (acc[i * 4 + j] - mu) * rs * ga[c + j] + be[c + j];
                if (val < 0.f) val = 0.f;
                o[j] = f2bf(val);
            }
            *(u16x4*)(&a_tile[row * TSTR + c]) = o;
        }
    } else {
        u16x4 o = {0, 0, 0, 0};
#pragma unroll
        for (int i = 0; i < 8; i++)
            *(u16x4*)(&a_tile[row * TSTR + c0 + i * 4]) = o;
    }
    __syncthreads();

    // GEMM: 4 waves x 16 rows, N=128, K=128
    int w = t >> 6, lane = t & 63;
    int quad = lane >> 4, ln = lane & 15;
    const f32x4 zf = {0.f, 0.f, 0.f, 0.f};
    f32x4 gacc[8];
#pragma unroll
    for (int j = 0; j < 8; j++) gacc[j] = zf;
#pragma unroll
    for (int kk = 0; kk < 4; kk++) {
        int ko = kk * 32 + quad * 8;
        bf16x8 a = *(const bf16x8*)(&a_tile[(w * 16 + ln) * TSTR + ko]);
#pragma unroll
        for (int nf = 0; nf < 8; nf++) {
            bf16x8 b = ld8(cw + (long long)(nf * 16 + ln) * GCH + ko);
            gacc[nf] = __builtin_amdgcn_mfma_f32_16x16x32_bf16(a, b, gacc[nf], 0, 0, 0);
        }
    }
#pragma unroll
    for (int nf = 0; nf < 8; nf++) {
        int col = nf * 16 + ln;
#pragma unroll
        for (int r4 = 0; r4 < 4; r4++) {
            int row2 = r0 + w * 16 + quad * 4 + r4;
            if (row2 < NN) zout[(long long)row2 * GCH + col] = f2bf(gacc[nf][r4]);
        }
    }
}

// ---- FUSED FINAL: agg(lg=7) into h[1] + LN256 + ReLU + GEMM(W2) -> out ----
#define FSTR 280
__global__ __launch_bounds__(256) void k_final_fused(
    const float* __restrict__ h,
    const int* __restrict__ rowptr, const int* __restrict__ ssrc,
    const float* __restrict__ sw,
    const unsigned short* __restrict__ zin,
    const float* __restrict__ cb,            // cbf + 7*128
    const unsigned short* __restrict__ w2t,
    const float* __restrict__ fgf, const float* __restrict__ fbf,
    const float* __restrict__ b2f,
    const int* __restrict__ flags,
    void* __restrict__ out)
{
    __shared__ __align__(16) unsigned short a_tile[FTM * FSTR];
    int t = threadIdx.x;
    int r0 = blockIdx.x * FTM;
    int row = t >> 2, part = t & 3;
    int r = r0 + row;
    int c0 = part * 32;

    float acc[32];   // agg for half1 chunk
    float h0v[32];   // half0 chunk
#pragma unroll
    for (int i = 0; i < 32; i++) acc[i] = 0.f;

    if (r < NN) {
        int beg = rowptr[r], end = rowptr[r + 1];
        const unsigned short* zb = zin + c0;
        int e = beg;
        for (; e + 1 < end; e += 2) {
            int s0 = ssrc[e], s1 = ssrc[e + 1];
            float w0 = sw[e], w1 = sw[e + 1];
            const unsigned short* z0 = zb + (long long)s0 * GCH;
            const unsigned short* z1 = zb + (long long)s1 * GCH;
            u16x8 a0 = *(const u16x8*)(z0);      u16x8 a1 = *(const u16x8*)(z0 + 8);
            u16x8 a2 = *(const u16x8*)(z0 + 16); u16x8 a3 = *(const u16x8*)(z0 + 24);
            u16x8 b0 = *(const u16x8*)(z1);      u16x8 b1 = *(const u16x8*)(z1 + 8);
            u16x8 b2 = *(const u16x8*)(z1 + 16); u16x8 b3 = *(const u16x8*)(z1 + 24);
#pragma unroll
            for (int j = 0; j < 8; j++) {
                acc[j]      += w0 * bf2f(a0[j]) + w1 * bf2f(b0[j]);
                acc[8 + j]  += w0 * bf2f(a1[j]) + w1 * bf2f(b1[j]);
                acc[16 + j] += w0 * bf2f(a2[j]) + w1 * bf2f(b2[j]);
                acc[24 + j] += w0 * bf2f(a3[j]) + w1 * bf2f(b3[j]);
            }
        }
        if (e < end) {
            int s0 = ssrc[e];
            float w0 = sw[e];
            const unsigned short* z0 = zb + (long long)s0 * GCH;
            u16x8 a0 = *(const u16x8*)(z0);      u16x8 a1 = *(const u16x8*)(z0 + 8);
            u16x8 a2 = *(const u16x8*)(z0 + 16); u16x8 a3 = *(const u16x8*)(z0 + 24);
#pragma unroll
            for (int j = 0; j < 8; j++) {
                acc[j]      += w0 * bf2f(a0[j]);
                acc[8 + j]  += w0 * bf2f(a1[j]);
                acc[16 + j] += w0 * bf2f(a2[j]);
                acc[24 + j] += w0 * bf2f(a3[j]);
            }
        }
    }

    float sum = 0.f, sq = 0.f;
    if (r < NN) {
        const float* hp = h + (long long)r * HIDC;
#pragma unroll
        for (int i = 0; i < 8; i++) {
            f32x4 h0 = *(const f32x4*)(hp + c0 + i * 4);          // half0
            f32x4 h1 = *(const f32x4*)(hp + GCH + c0 + i * 4);    // half1
#pragma unroll
            for (int j = 0; j < 4; j++) {
                float u0 = h0[j];
                float u1 = h1[j] + acc[i * 4 + j] + cb[c0 + i * 4 + j];
                h0v[i * 4 + j] = u0;
                acc[i * 4 + j] = u1;
                sum += u0 + u1;
                sq += u0 * u0 + u1 * u1;
            }
        }
    } else {
#pragma unroll
        for (int i = 0; i < 32; i++) h0v[i] = 0.f;
    }
    sum += __shfl_xor(sum, 1, 64);
    sum += __shfl_xor(sum, 2, 64);
    sq  += __shfl_xor(sq, 1, 64);
    sq  += __shfl_xor(sq, 2, 64);
    float mu = sum * (1.0f / HIDC);
    float var = sq * (1.0f / HIDC) - mu * mu;
    float rs = rsqrtf(var + EPSV);

    if (r < NN) {
#pragma unroll
        for (int i = 0; i < 8; i++) {
            int c = c0 + i * 4;
            u16x4 o0, o1;
#pragma unroll
            for (int j = 0; j < 4; j++) {
                float v0 = (h0v[i * 4 + j] - mu) * rs * fgf[c + j] + fbf[c + j];
                float v1 = (acc[i * 4 + j] - mu) * rs * fgf[GCH + c + j] + fbf[GCH + c + j];
                if (v0 < 0.f) v0 = 0.f;
                if (v1 < 0.f) v1 = 0.f;
                o0[j] = f2bf(v0);
                o1[j] = f2bf(v1);
            }
            *(u16x4*)(&a_tile[row * FSTR + c]) = o0;
            *(u16x4*)(&a_tile[row * FSTR + GCH + c]) = o1;
        }
    } else {
        u16x4 o = {0, 0, 0, 0};
#pragma unroll
        for (int i = 0; i < 8; i++) {
            *(u16x4*)(&a_tile[row * FSTR + c0 + i * 4]) = o;
            *(u16x4*)(&a_tile[row * FSTR + GCH + c0 + i * 4]) = o;
        }
    }
    __syncthreads();

    int w = t >> 6, lane = t & 63;
    int quad = lane >> 4, ln = lane & 15;
    const f32x4 zf = {0.f, 0.f, 0.f, 0.f};
    f32x4 gacc[3];
#pragma unroll
    for (int j = 0; j < 3; j++) gacc[j] = zf;
#pragma unroll
    for (int kk = 0; kk < 8; kk++) {
        int ko = kk * 32 + quad * 8;
        bf16x8 a = *(const bf16x8*)(&a_tile[(w * 16 + ln) * FSTR + ko]);
#pragma unroll
        for (int nf = 0; nf < 3; nf++) {
            bf16x8 b = ld8(w2t + (long long)(nf * 16 + ln) * HIDC + ko);
            gacc[nf] = __builtin_amdgcn_mfma_f32_16x16x32_bf16(a, b, gacc[nf], 0, 0, 0);
        }
    }
    int f32o = flags[1];
#pragma unroll
    for (int nf = 0; nf < 3; nf++) {
        int col = nf * 16 + ln;
        if (col >= OUTC) continue;
        float bias = b2f[col];
#pragma unroll
        for (int r4 = 0; r4 < 4; r4++) {
            int row2 = r0 + w * 16 + quad * 4 + r4;
            if (row2 < NN) {
                float val = gacc[nf][r4] + bias;
                long long o = (long long)row2 * OUTC + col;
                if (f32o) ((float*)out)[o] = val;
                else      ((unsigned short*)out)[o] = f2bf(val);
            }
        }
    }
}

extern "C" void kernel_launch(void* const* d_in, const int* in_sizes, int n_in,
                              void* d_out, int out_size, void* d_ws, size_t ws_size,
                              hipStream_t stream)
{
    const void* x       = d_in[0];
    const int*  ei      = (const int*)d_in[1];
    const void* ew      = d_in[2];
    const void* lin1_w  = d_in[3];
    const void* lin1_b  = d_in[4];
    const void* lin2_w  = d_in[5];
    const void* lin2_b  = d_in[6];
    const void* norm_g  = d_in[7];
    const void* norm_b  = d_in[8];
    const void* conv_w  = d_in[9];
    const void* conv_b  = d_in[10];
    const void* fnorm_g = d_in[11];
    const void* fnorm_b = d_in[12];

    char* ws = (char*)d_ws;
    size_t off = 0;
    auto alloc = [&](size_t bytes) { void* p = (void*)(ws + off); off += (bytes + 255) & ~255ull; return p; };

    float*          h      = (float*)alloc((size_t)NN * HIDC * 4);
    unsigned short* z0     = (unsigned short*)alloc((size_t)NN * GCH * 2);
    unsigned short* z1     = (unsigned short*)alloc((size_t)NN * GCH * 2);
    unsigned short* xb     = (unsigned short*)alloc((size_t)NN * INC * 2);
    unsigned short* w1t    = (unsigned short*)alloc((size_t)CVT_W1 * 2);
    unsigned short* cwt    = (unsigned short*)alloc((size_t)CVT_CW * 2);
    unsigned short* w2t    = (unsigned short*)alloc((size_t)CVT_W2 * 2);
    float*          b1f    = (float*)alloc(256 * 4);
    float*          ngf    = (float*)alloc(1024 * 4);
    float*          nbf    = (float*)alloc(1024 * 4);
    float*          cbf    = (float*)alloc(1024 * 4);
    float*          fgf    = (float*)alloc(256 * 4);
    float*          fbf    = (float*)alloc(256 * 4);
    float*          b2f    = (float*)alloc(48 * 4);
    int*            deg    = (int*)alloc((size_t)NN * 4);
    int*            rowptr = (int*)alloc(((size_t)NN + 1) * 4);
    int*            cursor = (int*)alloc((size_t)NN * 4);
    int*            ssrc   = (int*)alloc((size_t)NEDGE * 4);
    float*          sw     = (float*)alloc((size_t)NEDGE * 4);
    int*            flags  = (int*)alloc(256);
    int*            bsum   = (int*)alloc(SCAN_B * 4);
    int*            boff   = (int*)alloc(SCAN_B * 4);

    if (ws_size < off || n_in < 13) {
        float mv = 100.0f + (float)(ws_size >> 20) + ((n_in < 13) ? 10000.0f : 0.0f);
        k_marker<<<(out_size + 255) / 256, 256, 0, stream>>>(d_out, mv, out_size);
        return;
    }

    k_detect<<<196, 256, 0, stream>>>(ei, (const unsigned short*)x, flags, deg);
    k_convert<<<(CVT_TOT + 255) / 256, 256, 0, stream>>>(x, lin1_w, conv_w, lin2_w,
                                                         flags, xb, w1t, cwt, w2t);
    k_convert2<<<1, 256, 0, stream>>>(lin1_b, norm_g, norm_b, conv_b,
                                      fnorm_g, fnorm_b, lin2_b, flags,
                                      b1f, ngf, nbf, cbf, fgf, fbf, b2f);
    k_lin1<<<782, 256, 0, stream>>>(xb, w1t, b1f, h);

    k_count<<<(NEDGE / 2 + 255) / 256, 256, 0, stream>>>(ei, flags, deg);
    k_scan_a<<<SCAN_B, 256, 0, stream>>>(deg, bsum);
    k_scan_b<<<1, 64, 0, stream>>>(bsum, boff);
    k_scan_c<<<SCAN_B, 256, 0, stream>>>(deg, boff, rowptr, cursor);
    k_fill<<<(NEDGE / 2 + 255) / 256, 256, 0, stream>>>(ei, ew, flags, cursor, ssrc, sw);

    // block 0 standalone: z0 = relu(LN(h[:,1], lg=0)) @ cw[0]
    k_ln_gemm<<<391, 256, 0, stream>>>(h, cwt, ngf, nbf, 1, z0);

    // fused chain: agg(lg=i) + LN+GEMM(lg=i+1), i = 0..6
    const int NF = (NN + FTM - 1) / FTM;   // 782
    for (int i = 0; i < 7; i++) {
        unsigned short* zi = (i % 2 == 0) ? z0 : z1;
        unsigned short* zo = (i % 2 == 0) ? z1 : z0;
        int next = i + 1;
        k_fused<<<NF, 256, 0, stream>>>(h, rowptr, ssrc, sw, zi,
                                        cbf + i * GCH,
                                        cwt + (size_t)next * GCH * GCH,
                                        ngf + next * GCH, nbf + next * GCH,
                                        i & 1, zo);
    }
    // final: agg(lg=7, reads z1) + LN256 + GEMM(W2) -> out
    k_final_fused<<<NF, 256, 0, stream>>>(h, rowptr, ssrc, sw, z1,
                                          cbf + 7 * GCH, w2t, fgf, fbf, b2f,
                                          flags, d_out);
}

// Round 8
// 746.777 us; speedup vs baseline: 1.0052x; 1.0052x over previous
//
#include <hip/hip_runtime.h>
#include <stdint.h>

#define NN    50000
#define INC   128
#define HIDC  256
#define OUTC  40
#define GCH   128
#define NL    4
#define NG    2
#define NEDGE 600000
#define EPSV  1e-5f

typedef __bf16 bf16x8 __attribute__((ext_vector_type(8)));
typedef float  f32x4  __attribute__((ext_vector_type(4)));
typedef unsigned short u16x4 __attribute__((ext_vector_type(4)));

__device__ __forceinline__ float bf2f(unsigned short u) {
    union { float f; unsigned int i; } v;
    v.i = ((unsigned int)u) << 16;
    return v.f;
}
__device__ __forceinline__ unsigned short f2bf(float f) {
    union { float f; unsigned int i; } v;
    v.f = f;
    unsigned int u = v.i;
    u += 0x7FFFu + ((u >> 16) & 1u);   // RNE
    return (unsigned short)(u >> 16);
}
__device__ __forceinline__ float ldf(const void* p, int is_f32, long long i) {
    if (is_f32) return ((const float*)p)[i];
    return bf2f(((const unsigned short*)p)[i]);
}
__device__ __forceinline__ bf16x8 ld8(const unsigned short* p) {
    return *(const bf16x8*)p;
}

// ---- diagnostic marker ----
__global__ void k_marker(void* out, float val, int n) {
    int i = blockIdx.x * 256 + threadIdx.x;
    if (i < n) ((unsigned short*)out)[i] = f2bf(val);
}

// ---- zero deg + detect dtypes (proven) ----
__global__ void k_detect(const int* ei, const unsigned short* xprobe,
                         int* flags, int* deg) {
    int t = threadIdx.x;
    int gid = blockIdx.x * 256 + t;
    if (gid < NN) deg[gid] = 0;
    if (blockIdx.x == 0) {
        __shared__ int hi_or;
        __shared__ int wild_cnt;
        if (t == 0) { hi_or = 0; wild_cnt = 0; }
        __syncthreads();
        int acc = 0;
        for (int i = 0; i < 8; i++) acc |= ei[2 * (t + i * 256) + 1];
        if (acc) atomicOr(&hi_or, 1);
        int wild = 0;
        for (int i = 0; i < 2; i++) {
            unsigned short u = xprobe[t + i * 256];
            int e = (u >> 7) & 0xFF;
            if (e <= 0x30 || e >= 0xC0) wild++;
        }
        atomicAdd(&wild_cnt, wild);
        __syncthreads();
        if (t == 0) {
            flags[0] = hi_or ? 0 : 1;           // 1 => int64 edge_index
            flags[1] = (wild_cnt > 32) ? 1 : 0; // 1 => fp32 float tensors
        }
    }
}

// ---- one-time convert ----
#define CVT_X   6400000
#define CVT_W1  32768
#define CVT_CW  131072
#define CVT_W2  12288
#define CVT_TOT (CVT_X + CVT_W1 + CVT_CW + CVT_W2)

__global__ void k_convert(const void* x, const void* w1, const void* cw, const void* w2,
                          const int* flags,
                          unsigned short* xb, unsigned short* w1t,
                          unsigned short* cwt, unsigned short* w2t) {
    long long idx = (long long)blockIdx.x * 256 + threadIdx.x;
    if (idx >= CVT_TOT) return;
    int f32 = flags[1];
    if (idx < CVT_X) {
        xb[idx] = f2bf(ldf(x, f32, idx));
    } else if (idx < CVT_X + CVT_W1) {
        long long j = idx - CVT_X;
        int n = (int)(j >> 7), k = (int)(j & 127);
        w1t[j] = f2bf(ldf(w1, f32, (long long)k * HIDC + n));
    } else if (idx < CVT_X + CVT_W1 + CVT_CW) {
        long long j = idx - (CVT_X + CVT_W1);
        int lg = (int)(j >> 14);
        int rem = (int)(j & 16383);
        int n = rem >> 7, k = rem & 127;
        cwt[j] = f2bf(ldf(cw, f32, (long long)lg * GCH * GCH + (long long)k * GCH + n));
    } else {
        long long j = idx - (CVT_X + CVT_W1 + CVT_CW);
        int n = (int)(j >> 8), k = (int)(j & 255);
        w2t[j] = (n < OUTC) ? f2bf(ldf(w2, f32, (long long)k * OUTC + n)) : (unsigned short)0;
    }
}

__global__ void k_convert2(const void* b1, const void* ng, const void* nb, const void* cb,
                           const void* fg, const void* fb, const void* b2,
                           const int* flags,
                           float* b1f, float* ngf, float* nbf, float* cbf,
                           float* fgf, float* fbf, float* b2f) {
    int t = threadIdx.x;
    int f32 = flags[1];
    b1f[t] = ldf(b1, f32, t);
    fgf[t] = ldf(fg, f32, t);
    fbf[t] = ldf(fb, f32, t);
    if (t < 48) b2f[t] = (t < OUTC) ? ldf(b2, f32, t) : 0.0f;
    for (int i = 0; i < 4; i++) {
        int j = t + i * 256;
        ngf[j] = ldf(ng, f32, j);
        nbf[j] = ldf(nb, f32, j);
        cbf[j] = ldf(cb, f32, j);
    }
}

// ---- lin1: h = xb @ W1 + b1 ----
__global__ __launch_bounds__(256) void k_lin1(
    const unsigned short* __restrict__ xb,
    const unsigned short* __restrict__ w1t,
    const float* __restrict__ b1f,
    float* __restrict__ h)
{
    int bx = blockIdx.x;
    int r0 = (bx >> 1) * 128;
    int n0 = (bx & 1) * 128;
    int w = threadIdx.x >> 6, lane = threadIdx.x & 63;
    int quad = lane >> 4, ln = lane & 15;
    const f32x4 zf = {0.f, 0.f, 0.f, 0.f};
    const bf16x8 zb = {0, 0, 0, 0, 0, 0, 0, 0};
    f32x4 acc[2][8];
#pragma unroll
    for (int i = 0; i < 2; i++)
#pragma unroll
        for (int j = 0; j < 8; j++) acc[i][j] = zf;

#pragma unroll
    for (int kk = 0; kk < 4; kk++) {
        int ko = kk * 32 + quad * 8;
        bf16x8 a0, a1;
        {
            int r = r0 + w * 32 + ln;
            a0 = (r < NN) ? ld8(xb + (long long)r * INC + ko) : zb;
            r += 16;
            a1 = (r < NN) ? ld8(xb + (long long)r * INC + ko) : zb;
        }
#pragma unroll
        for (int nf = 0; nf < 8; nf++) {
            bf16x8 b = ld8(w1t + (long long)(n0 + nf * 16 + ln) * INC + ko);
            acc[0][nf] = __builtin_amdgcn_mfma_f32_16x16x32_bf16(a0, b, acc[0][nf], 0, 0, 0);
            acc[1][nf] = __builtin_amdgcn_mfma_f32_16x16x32_bf16(a1, b, acc[1][nf], 0, 0, 0);
        }
    }
#pragma unroll
    for (int mi = 0; mi < 2; mi++)
#pragma unroll
        for (int nf = 0; nf < 8; nf++) {
            int col = n0 + nf * 16 + ln;
            float bias = b1f[col];
#pragma unroll
            for (int r4 = 0; r4 < 4; r4++) {
                int row = r0 + w * 32 + mi * 16 + quad * 4 + r4;
                if (row < NN) h[(long long)row * HIDC + col] = acc[mi][nf][r4] + bias;
            }
        }
}

// ---- fused LN+ReLU+GEMM (R5-proven) ----
#define TSTR 152
__global__ __launch_bounds__(256) void k_ln_gemm(
    const float* __restrict__ h,
    const unsigned short* __restrict__ cw,
    const float* __restrict__ ga,
    const float* __restrict__ be,
    int in_half,
    unsigned short* __restrict__ z)
{
    __shared__ __align__(16) unsigned short a_tile[128 * TSTR];
    int t = threadIdx.x;
    int r0 = blockIdx.x * 128;

    int row = t >> 1, hh = t & 1;
    int r = r0 + row;
    const float* hp = h + (long long)r * HIDC + in_half * GCH + hh * 64;

    float sum = 0.f, sq = 0.f;
    float vbuf[64];
    if (r < NN) {
#pragma unroll
        for (int i = 0; i < 16; i++) {
            f32x4 v = *(const f32x4*)(hp + i * 4);
#pragma unroll
            for (int j = 0; j < 4; j++) {
                vbuf[i * 4 + j] = v[j];
                sum += v[j];
                sq += v[j] * v[j];
            }
        }
    } else {
#pragma unroll
        for (int i = 0; i < 64; i++) vbuf[i] = 0.f;
    }
    sum += __shfl_xor(sum, 1, 64);
    sq  += __shfl_xor(sq, 1, 64);
    float mu = sum * (1.0f / GCH);
    float var = sq * (1.0f / GCH) - mu * mu;
    float rs = rsqrtf(var + EPSV);

#pragma unroll
    for (int i = 0; i < 16; i++) {
        int c = hh * 64 + i * 4;
        u16x4 o;
#pragma unroll
        for (int j = 0; j < 4; j++) {
            float val = (vbuf[i * 4 + j] - mu) * rs * ga[c + j] + be[c + j];
            if (val < 0.f) val = 0.f;
            o[j] = f2bf(val);
        }
        *(u16x4*)(&a_tile[row * TSTR + c]) = o;
    }
    __syncthreads();

    int w = t >> 6, lane = t & 63;
    int quad = lane >> 4, ln = lane & 15;
    const f32x4 zf = {0.f, 0.f, 0.f, 0.f};
    f32x4 acc[2][8];
#pragma unroll
    for (int i = 0; i < 2; i++)
#pragma unroll
        for (int j = 0; j < 8; j++) acc[i][j] = zf;

#pragma unroll
    for (int kk = 0; kk < 4; kk++) {
        int ko = kk * 32 + quad * 8;
        bf16x8 a0 = *(const bf16x8*)(&a_tile[(w * 32 + ln) * TSTR + ko]);
        bf16x8 a1 = *(const bf16x8*)(&a_tile[(w * 32 + 16 + ln) * TSTR + ko]);
#pragma unroll
        for (int nf = 0; nf < 8; nf++) {
            bf16x8 b = ld8(cw + (long long)(nf * 16 + ln) * GCH + ko);
            acc[0][nf] = __builtin_amdgcn_mfma_f32_16x16x32_bf16(a0, b, acc[0][nf], 0, 0, 0);
            acc[1][nf] = __builtin_amdgcn_mfma_f32_16x16x32_bf16(a1, b, acc[1][nf], 0, 0, 0);
        }
    }
#pragma unroll
    for (int mi = 0; mi < 2; mi++)
#pragma unroll
        for (int nf = 0; nf < 8; nf++) {
            int col = nf * 16 + ln;
#pragma unroll
            for (int r4 = 0; r4 < 4; r4++) {
                int row2 = r0 + w * 32 + mi * 16 + quad * 4 + r4;
                if (row2 < NN) z[(long long)row2 * GCH + col] = f2bf(acc[mi][nf][r4]);
            }
        }
}

// ---- CSR build ----
__global__ void k_count(const int* __restrict__ ei, const int* __restrict__ flags,
                        int* __restrict__ deg) {
    int e = (blockIdx.x * 256 + threadIdx.x) * 2;
    if (e >= NEDGE) return;
    int d0, d1;
    if (flags[0]) {
        int4 v = *(const int4*)(ei + 2 * (NEDGE + e));
        d0 = v.x; d1 = v.z;
    } else {
        int2 v = *(const int2*)(ei + NEDGE + e);
        d0 = v.x; d1 = v.y;
    }
    atomicAdd(&deg[d0], 1);
    if (e + 1 < NEDGE) atomicAdd(&deg[d1], 1);
}

#define SCAN_B 49
__global__ void k_scan_a(const int* __restrict__ deg, int* __restrict__ bsum) {
    __shared__ int part[256];
    int b = blockIdx.x, t = threadIdx.x;
    int base = b * 1024 + t * 4;
    int s = 0;
#pragma unroll
    for (int j = 0; j < 4; j++) {
        int i = base + j;
        if (i < NN) s += deg[i];
    }
    part[t] = s;
    __syncthreads();
    for (int off = 128; off > 0; off >>= 1) {
        if (t < off) part[t] += part[t + off];
        __syncthreads();
    }
    if (t == 0) bsum[b] = part[0];
}

__global__ void k_scan_b(const int* __restrict__ bsum, int* __restrict__ boff) {
    if (threadIdx.x == 0) {
        int run = 0;
        for (int i = 0; i < SCAN_B; i++) { boff[i] = run; run += bsum[i]; }
    }
}

__global__ void k_scan_c(const int* __restrict__ deg, const int* __restrict__ boff,
                         int* __restrict__ rowptr, int* __restrict__ cursor) {
    __shared__ int part[256];
    int b = blockIdx.x, t = threadIdx.x;
    int base = b * 1024 + t * 4;
    int v[4];
    int s = 0;
#pragma unroll
    for (int j = 0; j < 4; j++) {
        int i = base + j;
        v[j] = (i < NN) ? deg[i] : 0;
        s += v[j];
    }
    part[t] = s;
    __syncthreads();
    for (int off = 1; off < 256; off <<= 1) {
        int x = (t >= off) ? part[t - off] : 0;
        __syncthreads();
        part[t] += x;
        __syncthreads();
    }
    int run = boff[b] + part[t] - s;
#pragma unroll
    for (int j = 0; j < 4; j++) {
        int i = base + j;
        if (i < NN) { rowptr[i] = run; cursor[i] = run; }
        run += v[j];
    }
    if (b == SCAN_B - 1 && t == 255) rowptr[NN] = NEDGE;
}

// R5-proven fill: 1 edge/thread, two arrays (42 us measured; packed int2 regressed)
__global__ void k_fill(const int* __restrict__ ei, const void* __restrict__ ew,
                       const int* __restrict__ flags,
                       int* __restrict__ cursor, int* __restrict__ ssrc,
                       float* __restrict__ sw) {
    int e = blockIdx.x * 256 + threadIdx.x;
    if (e < NEDGE) {
        int is64 = flags[0];
        int d = is64 ? ei[2 * (NEDGE + e)] : ei[NEDGE + e];
        int s = is64 ? ei[2 * e] : ei[e];
        int p = atomicAdd(&cursor[d], 1);
        ssrc[p] = s;
        sw[p] = ldf(ew, flags[1], e);
    }
}

// ---- CHANNEL-CHUNKED aggregate: grid.y = chunk of 32 channels ----
// per-pass z working set = 50000*32*2B = 3.2 MB -> fits each XCD's 4 MB L2
__global__ __launch_bounds__(256) void k_agg(
    const int* __restrict__ rowptr, const int* __restrict__ ssrc,
    const float* __restrict__ sw, const unsigned short* __restrict__ z,
    const float* __restrict__ cb,
    float* __restrict__ h, int out_half)
{
    int node = blockIdx.x * 32 + (threadIdx.x >> 3);
    if (node >= NN) return;
    int c = blockIdx.y * 32 + (threadIdx.x & 7) * 4;   // 4 channels/thread
    int beg = rowptr[node], end = rowptr[node + 1];
    const unsigned short* zb = z + c;
    float a0 = 0.f, a1 = 0.f, a2 = 0.f, a3 = 0.f;
    int e = beg;
    for (; e + 3 < end; e += 4) {
        int s0 = ssrc[e], s1 = ssrc[e + 1], s2 = ssrc[e + 2], s3 = ssrc[e + 3];
        float w0 = sw[e], w1 = sw[e + 1], w2 = sw[e + 2], w3 = sw[e + 3];
        u16x4 v0 = *(const u16x4*)(zb + (long long)s0 * GCH);
        u16x4 v1 = *(const u16x4*)(zb + (long long)s1 * GCH);
        u16x4 v2 = *(const u16x4*)(zb + (long long)s2 * GCH);
        u16x4 v3 = *(const u16x4*)(zb + (long long)s3 * GCH);
        a0 += w0 * bf2f(v0[0]) + w1 * bf2f(v1[0]) + w2 * bf2f(v2[0]) + w3 * bf2f(v3[0]);
        a1 += w0 * bf2f(v0[1]) + w1 * bf2f(v1[1]) + w2 * bf2f(v2[1]) + w3 * bf2f(v3[1]);
        a2 += w0 * bf2f(v0[2]) + w1 * bf2f(v1[2]) + w2 * bf2f(v2[2]) + w3 * bf2f(v3[2]);
        a3 += w0 * bf2f(v0[3]) + w1 * bf2f(v1[3]) + w2 * bf2f(v2[3]) + w3 * bf2f(v3[3]);
    }
    for (; e < end; e++) {
        int s = ssrc[e];
        float wt = sw[e];
        u16x4 v = *(const u16x4*)(zb + (long long)s * GCH);
        a0 += wt * bf2f(v[0]);
        a1 += wt * bf2f(v[1]);
        a2 += wt * bf2f(v[2]);
        a3 += wt * bf2f(v[3]);
    }
    float* hp = h + (long long)node * HIDC + out_half * GCH + c;
    f32x4 v = *(f32x4*)hp;
    v[0] += a0 + cb[c];
    v[1] += a1 + cb[c + 1];
    v[2] += a2 + cb[c + 2];
    v[3] += a3 + cb[c + 3];
    *(f32x4*)hp = v;
}

// ---- final: out = relu(LN256(h)) @ W2 + b2 (R5-proven) ----
#define FSTR 280
__global__ __launch_bounds__(256) void k_final(
    const float* __restrict__ h,
    const unsigned short* __restrict__ w2t,
    const float* __restrict__ fgf, const float* __restrict__ fbf,
    const float* __restrict__ b2f,
    const int* __restrict__ flags,
    void* __restrict__ out)
{
    __shared__ __align__(16) unsigned short a_tile[64 * FSTR];
    int t = threadIdx.x;
    int r0 = blockIdx.x * 64;

    int row = t >> 2, q = t & 3;
    int r = r0 + row;
    const float* hp = h + (long long)r * HIDC + q * 64;
    float sum = 0.f, sq = 0.f;
    float vbuf[64];
    if (r < NN) {
#pragma unroll
        for (int i = 0; i < 16; i++) {
            f32x4 v = *(const f32x4*)(hp + i * 4);
#pragma unroll
            for (int j = 0; j < 4; j++) {
                vbuf[i * 4 + j] = v[j];
                sum += v[j];
                sq += v[j] * v[j];
            }
        }
    } else {
#pragma unroll
        for (int i = 0; i < 64; i++) vbuf[i] = 0.f;
    }
    sum += __shfl_xor(sum, 1, 64);
    sum += __shfl_xor(sum, 2, 64);
    sq  += __shfl_xor(sq, 1, 64);
    sq  += __shfl_xor(sq, 2, 64);
    float mu = sum * (1.0f / HIDC);
    float var = sq * (1.0f / HIDC) - mu * mu;
    float rs = rsqrtf(var + EPSV);

#pragma unroll
    for (int i = 0; i < 16; i++) {
        int c = q * 64 + i * 4;
        u16x4 o;
#pragma unroll
        for (int j = 0; j < 4; j++) {
            float val = (vbuf[i * 4 + j] - mu) * rs * fgf[c + j] + fbf[c + j];
            if (val < 0.f) val = 0.f;
            o[j] = f2bf(val);
        }
        *(u16x4*)(&a_tile[row * FSTR + c]) = o;
    }
    __syncthreads();

    int w = t >> 6, lane = t & 63;
    int quad = lane >> 4, ln = lane & 15;
    const f32x4 zf = {0.f, 0.f, 0.f, 0.f};
    f32x4 acc[3];
#pragma unroll
    for (int j = 0; j < 3; j++) acc[j] = zf;
#pragma unroll
    for (int kk = 0; kk < 8; kk++) {
        int ko = kk * 32 + quad * 8;
        bf16x8 a = *(const bf16x8*)(&a_tile[(w * 16 + ln) * FSTR + ko]);
#pragma unroll
        for (int nf = 0; nf < 3; nf++) {
            bf16x8 b = ld8(w2t + (long long)(nf * 16 + ln) * HIDC + ko);
            acc[nf] = __builtin_amdgcn_mfma_f32_16x16x32_bf16(a, b, acc[nf], 0, 0, 0);
        }
    }
    int f32o = flags[1];
#pragma unroll
    for (int nf = 0; nf < 3; nf++) {
        int col = nf * 16 + ln;
        if (col >= OUTC) continue;
        float bias = b2f[col];
#pragma unroll
        for (int r4 = 0; r4 < 4; r4++) {
            int row2 = r0 + w * 16 + quad * 4 + r4;
            if (row2 < NN) {
                float val = acc[nf][r4] + bias;
                long long o = (long long)row2 * OUTC + col;
                if (f32o) ((float*)out)[o] = val;
                else      ((unsigned short*)out)[o] = f2bf(val);
            }
        }
    }
}

extern "C" void kernel_launch(void* const* d_in, const int* in_sizes, int n_in,
                              void* d_out, int out_size, void* d_ws, size_t ws_size,
                              hipStream_t stream)
{
    const void* x       = d_in[0];
    const int*  ei      = (const int*)d_in[1];
    const void* ew      = d_in[2];
    const void* lin1_w  = d_in[3];
    const void* lin1_b  = d_in[4];
    const void* lin2_w  = d_in[5];
    const void* lin2_b  = d_in[6];
    const void* norm_g  = d_in[7];
    const void* norm_b  = d_in[8];
    const void* conv_w  = d_in[9];
    const void* conv_b  = d_in[10];
    const void* fnorm_g = d_in[11];
    const void* fnorm_b = d_in[12];

    char* ws = (char*)d_ws;
    size_t off = 0;
    auto alloc = [&](size_t bytes) { void* p = (void*)(ws + off); off += (bytes + 255) & ~255ull; return p; };

    float*          h      = (float*)alloc((size_t)NN * HIDC * 4);
    unsigned short* z      = (unsigned short*)alloc((size_t)NN * GCH * 2);
    unsigned short* xb     = (unsigned short*)alloc((size_t)NN * INC * 2);
    unsigned short* w1t    = (unsigned short*)alloc((size_t)CVT_W1 * 2);
    unsigned short* cwt    = (unsigned short*)alloc((size_t)CVT_CW * 2);
    unsigned short* w2t    = (unsigned short*)alloc((size_t)CVT_W2 * 2);
    float*          b1f    = (float*)alloc(256 * 4);
    float*          ngf    = (float*)alloc(1024 * 4);
    float*          nbf    = (float*)alloc(1024 * 4);
    float*          cbf    = (float*)alloc(1024 * 4);
    float*          fgf    = (float*)alloc(256 * 4);
    float*          fbf    = (float*)alloc(256 * 4);
    float*          b2f    = (float*)alloc(48 * 4);
    int*            deg    = (int*)alloc((size_t)NN * 4);
    int*            rowptr = (int*)alloc(((size_t)NN + 1) * 4);
    int*            cursor = (int*)alloc((size_t)NN * 4);
    int*            ssrc   = (int*)alloc((size_t)NEDGE * 4);
    float*          sw     = (float*)alloc((size_t)NEDGE * 4);
    int*            flags  = (int*)alloc(256);
    int*            bsum   = (int*)alloc(SCAN_B * 4);
    int*            boff   = (int*)alloc(SCAN_B * 4);

    if (ws_size < off || n_in < 13) {
        float mv = 100.0f + (float)(ws_size >> 20) + ((n_in < 13) ? 10000.0f : 0.0f);
        k_marker<<<(out_size + 255) / 256, 256, 0, stream>>>(d_out, mv, out_size);
        return;
    }

    k_detect<<<196, 256, 0, stream>>>(ei, (const unsigned short*)x, flags, deg);
    k_convert<<<(CVT_TOT + 255) / 256, 256, 0, stream>>>(x, lin1_w, conv_w, lin2_w,
                                                         flags, xb, w1t, cwt, w2t);
    k_convert2<<<1, 256, 0, stream>>>(lin1_b, norm_g, norm_b, conv_b,
                                      fnorm_g, fnorm_b, lin2_b, flags,
                                      b1f, ngf, nbf, cbf, fgf, fbf, b2f);
    k_lin1<<<782, 256, 0, stream>>>(xb, w1t, b1f, h);

    k_count<<<(NEDGE / 2 + 255) / 256, 256, 0, stream>>>(ei, flags, deg);
    k_scan_a<<<SCAN_B, 256, 0, stream>>>(deg, bsum);
    k_scan_b<<<1, 64, 0, stream>>>(bsum, boff);
    k_scan_c<<<SCAN_B, 256, 0, stream>>>(deg, boff, rowptr, cursor);
    k_fill<<<(NEDGE + 255) / 256, 256, 0, stream>>>(ei, ew, flags, cursor, ssrc, sw);

    const int AGG_BX = (NN + 31) / 32;   // 1563
    for (int l = 0; l < NL; l++) {
        for (int g = 0; g < NG; g++) {
            int lg = l * NG + g;
            int in_half = g ^ 1;
            k_ln_gemm<<<391, 256, 0, stream>>>(h, cwt + (size_t)lg * GCH * GCH,
                                               ngf + lg * GCH, nbf + lg * GCH,
                                               in_half, z);
            k_agg<<<dim3(AGG_BX, 4), 256, 0, stream>>>(rowptr, ssrc, sw, z,
                                                       cbf + lg * GCH, h, g);
        }
    }
    k_final<<<782, 256, 0, stream>>>(h, w2t, fgf, fbf, b2f, flags, d_out);
}

// Round 9
// 657.144 us; speedup vs baseline: 1.1423x; 1.1364x over previous
//
#include <hip/hip_runtime.h>
#include <stdint.h>

#define NN    50000
#define INC   128
#define HIDC  256
#define OUTC  40
#define GCH   128
#define NL    4
#define NG    2
#define NEDGE 600000
#define EPSV  1e-5f

typedef __bf16 bf16x8 __attribute__((ext_vector_type(8)));
typedef float  f32x4  __attribute__((ext_vector_type(4)));
typedef unsigned short u16x4 __attribute__((ext_vector_type(4)));
typedef unsigned short u16x8 __attribute__((ext_vector_type(8)));

__device__ __forceinline__ float bf2f(unsigned short u) {
    union { float f; unsigned int i; } v;
    v.i = ((unsigned int)u) << 16;
    return v.f;
}
__device__ __forceinline__ unsigned short f2bf(float f) {
    union { float f; unsigned int i; } v;
    v.f = f;
    unsigned int u = v.i;
    u += 0x7FFFu + ((u >> 16) & 1u);   // RNE
    return (unsigned short)(u >> 16);
}
__device__ __forceinline__ float ldf(const void* p, int is_f32, long long i) {
    if (is_f32) return ((const float*)p)[i];
    return bf2f(((const unsigned short*)p)[i]);
}
__device__ __forceinline__ bf16x8 ld8(const unsigned short* p) {
    return *(const bf16x8*)p;
}

// ---- diagnostic marker ----
__global__ void k_marker(void* out, float val, int n) {
    int i = blockIdx.x * 256 + threadIdx.x;
    if (i < n) ((unsigned short*)out)[i] = f2bf(val);
}

// ---- zero deg + detect dtypes (proven) ----
__global__ void k_detect(const int* ei, const unsigned short* xprobe,
                         int* flags, int* deg) {
    int t = threadIdx.x;
    int gid = blockIdx.x * 256 + t;
    if (gid < NN) deg[gid] = 0;
    if (blockIdx.x == 0) {
        __shared__ int hi_or;
        __shared__ int wild_cnt;
        if (t == 0) { hi_or = 0; wild_cnt = 0; }
        __syncthreads();
        int acc = 0;
        for (int i = 0; i < 8; i++) acc |= ei[2 * (t + i * 256) + 1];
        if (acc) atomicOr(&hi_or, 1);
        int wild = 0;
        for (int i = 0; i < 2; i++) {
            unsigned short u = xprobe[t + i * 256];
            int e = (u >> 7) & 0xFF;
            if (e <= 0x30 || e >= 0xC0) wild++;
        }
        atomicAdd(&wild_cnt, wild);
        __syncthreads();
        if (t == 0) {
            flags[0] = hi_or ? 0 : 1;           // 1 => int64 edge_index
            flags[1] = (wild_cnt > 32) ? 1 : 0; // 1 => fp32 float tensors
        }
    }
}

// ---- one-time convert ----
#define CVT_X   6400000
#define CVT_W1  32768
#define CVT_CW  131072
#define CVT_W2  12288
#define CVT_TOT (CVT_X + CVT_W1 + CVT_CW + CVT_W2)

__global__ void k_convert(const void* x, const void* w1, const void* cw, const void* w2,
                          const int* flags,
                          unsigned short* xb, unsigned short* w1t,
                          unsigned short* cwt, unsigned short* w2t) {
    long long idx = (long long)blockIdx.x * 256 + threadIdx.x;
    if (idx >= CVT_TOT) return;
    int f32 = flags[1];
    if (idx < CVT_X) {
        xb[idx] = f2bf(ldf(x, f32, idx));
    } else if (idx < CVT_X + CVT_W1) {
        long long j = idx - CVT_X;
        int n = (int)(j >> 7), k = (int)(j & 127);
        w1t[j] = f2bf(ldf(w1, f32, (long long)k * HIDC + n));
    } else if (idx < CVT_X + CVT_W1 + CVT_CW) {
        long long j = idx - (CVT_X + CVT_W1);
        int lg = (int)(j >> 14);
        int rem = (int)(j & 16383);
        int n = rem >> 7, k = rem & 127;
        cwt[j] = f2bf(ldf(cw, f32, (long long)lg * GCH * GCH + (long long)k * GCH + n));
    } else {
        long long j = idx - (CVT_X + CVT_W1 + CVT_CW);
        int n = (int)(j >> 8), k = (int)(j & 255);
        w2t[j] = (n < OUTC) ? f2bf(ldf(w2, f32, (long long)k * OUTC + n)) : (unsigned short)0;
    }
}

__global__ void k_convert2(const void* b1, const void* ng, const void* nb, const void* cb,
                           const void* fg, const void* fb, const void* b2,
                           const int* flags,
                           float* b1f, float* ngf, float* nbf, float* cbf,
                           float* fgf, float* fbf, float* b2f) {
    int t = threadIdx.x;
    int f32 = flags[1];
    b1f[t] = ldf(b1, f32, t);
    fgf[t] = ldf(fg, f32, t);
    fbf[t] = ldf(fb, f32, t);
    if (t < 48) b2f[t] = (t < OUTC) ? ldf(b2, f32, t) : 0.0f;
    for (int i = 0; i < 4; i++) {
        int j = t + i * 256;
        ngf[j] = ldf(ng, f32, j);
        nbf[j] = ldf(nb, f32, j);
        cbf[j] = ldf(cb, f32, j);
    }
}

// ---- lin1: h = xb @ W1 + b1 ----
__global__ __launch_bounds__(256) void k_lin1(
    const unsigned short* __restrict__ xb,
    const unsigned short* __restrict__ w1t,
    const float* __restrict__ b1f,
    float* __restrict__ h)
{
    int bx = blockIdx.x;
    int r0 = (bx >> 1) * 128;
    int n0 = (bx & 1) * 128;
    int w = threadIdx.x >> 6, lane = threadIdx.x & 63;
    int quad = lane >> 4, ln = lane & 15;
    const f32x4 zf = {0.f, 0.f, 0.f, 0.f};
    const bf16x8 zb = {0, 0, 0, 0, 0, 0, 0, 0};
    f32x4 acc[2][8];
#pragma unroll
    for (int i = 0; i < 2; i++)
#pragma unroll
        for (int j = 0; j < 8; j++) acc[i][j] = zf;

#pragma unroll
    for (int kk = 0; kk < 4; kk++) {
        int ko = kk * 32 + quad * 8;
        bf16x8 a0, a1;
        {
            int r = r0 + w * 32 + ln;
            a0 = (r < NN) ? ld8(xb + (long long)r * INC + ko) : zb;
            r += 16;
            a1 = (r < NN) ? ld8(xb + (long long)r * INC + ko) : zb;
        }
#pragma unroll
        for (int nf = 0; nf < 8; nf++) {
            bf16x8 b = ld8(w1t + (long long)(n0 + nf * 16 + ln) * INC + ko);
            acc[0][nf] = __builtin_amdgcn_mfma_f32_16x16x32_bf16(a0, b, acc[0][nf], 0, 0, 0);
            acc[1][nf] = __builtin_amdgcn_mfma_f32_16x16x32_bf16(a1, b, acc[1][nf], 0, 0, 0);
        }
    }
#pragma unroll
    for (int mi = 0; mi < 2; mi++)
#pragma unroll
        for (int nf = 0; nf < 8; nf++) {
            int col = n0 + nf * 16 + ln;
            float bias = b1f[col];
#pragma unroll
            for (int r4 = 0; r4 < 4; r4++) {
                int row = r0 + w * 32 + mi * 16 + quad * 4 + r4;
                if (row < NN) h[(long long)row * HIDC + col] = acc[mi][nf][r4] + bias;
            }
        }
}

// ---- fused LN+ReLU+GEMM (R5-proven) ----
#define TSTR 152
__global__ __launch_bounds__(256) void k_ln_gemm(
    const float* __restrict__ h,
    const unsigned short* __restrict__ cw,
    const float* __restrict__ ga,
    const float* __restrict__ be,
    int in_half,
    unsigned short* __restrict__ z)
{
    __shared__ __align__(16) unsigned short a_tile[128 * TSTR];
    int t = threadIdx.x;
    int r0 = blockIdx.x * 128;

    int row = t >> 1, hh = t & 1;
    int r = r0 + row;
    const float* hp = h + (long long)r * HIDC + in_half * GCH + hh * 64;

    float sum = 0.f, sq = 0.f;
    float vbuf[64];
    if (r < NN) {
#pragma unroll
        for (int i = 0; i < 16; i++) {
            f32x4 v = *(const f32x4*)(hp + i * 4);
#pragma unroll
            for (int j = 0; j < 4; j++) {
                vbuf[i * 4 + j] = v[j];
                sum += v[j];
                sq += v[j] * v[j];
            }
        }
    } else {
#pragma unroll
        for (int i = 0; i < 64; i++) vbuf[i] = 0.f;
    }
    sum += __shfl_xor(sum, 1, 64);
    sq  += __shfl_xor(sq, 1, 64);
    float mu = sum * (1.0f / GCH);
    float var = sq * (1.0f / GCH) - mu * mu;
    float rs = rsqrtf(var + EPSV);

#pragma unroll
    for (int i = 0; i < 16; i++) {
        int c = hh * 64 + i * 4;
        u16x4 o;
#pragma unroll
        for (int j = 0; j < 4; j++) {
            float val = (vbuf[i * 4 + j] - mu) * rs * ga[c + j] + be[c + j];
            if (val < 0.f) val = 0.f;
            o[j] = f2bf(val);
        }
        *(u16x4*)(&a_tile[row * TSTR + c]) = o;
    }
    __syncthreads();

    int w = t >> 6, lane = t & 63;
    int quad = lane >> 4, ln = lane & 15;
    const f32x4 zf = {0.f, 0.f, 0.f, 0.f};
    f32x4 acc[2][8];
#pragma unroll
    for (int i = 0; i < 2; i++)
#pragma unroll
        for (int j = 0; j < 8; j++) acc[i][j] = zf;

#pragma unroll
    for (int kk = 0; kk < 4; kk++) {
        int ko = kk * 32 + quad * 8;
        bf16x8 a0 = *(const bf16x8*)(&a_tile[(w * 32 + ln) * TSTR + ko]);
        bf16x8 a1 = *(const bf16x8*)(&a_tile[(w * 32 + 16 + ln) * TSTR + ko]);
#pragma unroll
        for (int nf = 0; nf < 8; nf++) {
            bf16x8 b = ld8(cw + (long long)(nf * 16 + ln) * GCH + ko);
            acc[0][nf] = __builtin_amdgcn_mfma_f32_16x16x32_bf16(a0, b, acc[0][nf], 0, 0, 0);
            acc[1][nf] = __builtin_amdgcn_mfma_f32_16x16x32_bf16(a1, b, acc[1][nf], 0, 0, 0);
        }
    }
#pragma unroll
    for (int mi = 0; mi < 2; mi++)
#pragma unroll
        for (int nf = 0; nf < 8; nf++) {
            int col = nf * 16 + ln;
#pragma unroll
            for (int r4 = 0; r4 < 4; r4++) {
                int row2 = r0 + w * 32 + mi * 16 + quad * 4 + r4;
                if (row2 < NN) z[(long long)row2 * GCH + col] = f2bf(acc[mi][nf][r4]);
            }
        }
}

// ---- CSR build ----
__global__ void k_count(const int* __restrict__ ei, const int* __restrict__ flags,
                        int* __restrict__ deg) {
    int e = (blockIdx.x * 256 + threadIdx.x) * 2;
    if (e >= NEDGE) return;
    int d0, d1;
    if (flags[0]) {
        int4 v = *(const int4*)(ei + 2 * (NEDGE + e));
        d0 = v.x; d1 = v.z;
    } else {
        int2 v = *(const int2*)(ei + NEDGE + e);
        d0 = v.x; d1 = v.y;
    }
    atomicAdd(&deg[d0], 1);
    if (e + 1 < NEDGE) atomicAdd(&deg[d1], 1);
}

#define SCAN_B 49
__global__ void k_scan_a(const int* __restrict__ deg, int* __restrict__ bsum) {
    __shared__ int part[256];
    int b = blockIdx.x, t = threadIdx.x;
    int base = b * 1024 + t * 4;
    int s = 0;
#pragma unroll
    for (int j = 0; j < 4; j++) {
        int i = base + j;
        if (i < NN) s += deg[i];
    }
    part[t] = s;
    __syncthreads();
    for (int off = 128; off > 0; off >>= 1) {
        if (t < off) part[t] += part[t + off];
        __syncthreads();
    }
    if (t == 0) bsum[b] = part[0];
}

__global__ void k_scan_b(const int* __restrict__ bsum, int* __restrict__ boff) {
    if (threadIdx.x == 0) {
        int run = 0;
        for (int i = 0; i < SCAN_B; i++) { boff[i] = run; run += bsum[i]; }
    }
}

__global__ void k_scan_c(const int* __restrict__ deg, const int* __restrict__ boff,
                         int* __restrict__ rowptr, int* __restrict__ cursor) {
    __shared__ int part[256];
    int b = blockIdx.x, t = threadIdx.x;
    int base = b * 1024 + t * 4;
    int v[4];
    int s = 0;
#pragma unroll
    for (int j = 0; j < 4; j++) {
        int i = base + j;
        v[j] = (i < NN) ? deg[i] : 0;
        s += v[j];
    }
    part[t] = s;
    __syncthreads();
    for (int off = 1; off < 256; off <<= 1) {
        int x = (t >= off) ? part[t - off] : 0;
        __syncthreads();
        part[t] += x;
        __syncthreads();
    }
    int run = boff[b] + part[t] - s;
#pragma unroll
    for (int j = 0; j < 4; j++) {
        int i = base + j;
        if (i < NN) { rowptr[i] = run; cursor[i] = run; }
        run += v[j];
    }
    if (b == SCAN_B - 1 && t == 255) rowptr[NN] = NEDGE;
}

// two-array fill + 2-edge batching (two independent atomics in flight)
__global__ void k_fill(const int* __restrict__ ei, const void* __restrict__ ew,
                       const int* __restrict__ flags,
                       int* __restrict__ cursor, int* __restrict__ ssrc,
                       float* __restrict__ sw) {
    int e = (blockIdx.x * 256 + threadIdx.x) * 2;
    if (e >= NEDGE) return;
    int is64 = flags[0];
    int f32 = flags[1];
    int d0, s0, d1 = 0, s1 = 0;
    int has1 = (e + 1 < NEDGE);
    if (is64) {
        d0 = ei[2 * (NEDGE + e)];
        s0 = ei[2 * e];
        if (has1) { d1 = ei[2 * (NEDGE + e) + 2]; s1 = ei[2 * e + 2]; }
    } else {
        d0 = ei[NEDGE + e];
        s0 = ei[e];
        if (has1) { d1 = ei[NEDGE + e + 1]; s1 = ei[e + 1]; }
    }
    int p0 = atomicAdd(&cursor[d0], 1);
    int p1 = has1 ? atomicAdd(&cursor[d1], 1) : 0;
    ssrc[p0] = s0;
    sw[p0] = ldf(ew, f32, e);
    if (has1) {
        ssrc[p1] = s1;
        sw[p1] = ldf(ew, f32, e + 1);
    }
}

// ---- aggregate: h[:, out_half] += segsum(w * z[src]) + conv_b[lg] ----
// 16 thr/node x u16x8 (16B/lane), 8-edge unroll: 8 outstanding 16B gathers/thread
__global__ __launch_bounds__(256) void k_agg(
    const int* __restrict__ rowptr, const int* __restrict__ ssrc,
    const float* __restrict__ sw, const unsigned short* __restrict__ z,
    const float* __restrict__ cb,
    float* __restrict__ h, int out_half)
{
    int node = blockIdx.x * 16 + (threadIdx.x >> 4);
    if (node >= NN) return;
    int c8 = (threadIdx.x & 15) << 3;   // 8 channels/thread
    int beg = rowptr[node], end = rowptr[node + 1];
    const unsigned short* zb = z + c8;
    float acc[8];
#pragma unroll
    for (int j = 0; j < 8; j++) acc[j] = 0.f;

    int e = beg;
    for (; e + 7 < end; e += 8) {
        int   s[8];
        float w[8];
        u16x8 v[8];
#pragma unroll
        for (int i = 0; i < 8; i++) { s[i] = ssrc[e + i]; w[i] = sw[e + i]; }
#pragma unroll
        for (int i = 0; i < 8; i++) v[i] = *(const u16x8*)(zb + (long long)s[i] * GCH);
#pragma unroll
        for (int i = 0; i < 8; i++)
#pragma unroll
            for (int j = 0; j < 8; j++) acc[j] += w[i] * bf2f(v[i][j]);
    }
    if (e + 3 < end) {
        int   s[4];
        float w[4];
        u16x8 v[4];
#pragma unroll
        for (int i = 0; i < 4; i++) { s[i] = ssrc[e + i]; w[i] = sw[e + i]; }
#pragma unroll
        for (int i = 0; i < 4; i++) v[i] = *(const u16x8*)(zb + (long long)s[i] * GCH);
#pragma unroll
        for (int i = 0; i < 4; i++)
#pragma unroll
            for (int j = 0; j < 8; j++) acc[j] += w[i] * bf2f(v[i][j]);
        e += 4;
    }
    for (; e < end; e++) {
        int s0 = ssrc[e];
        float w0 = sw[e];
        u16x8 v = *(const u16x8*)(zb + (long long)s0 * GCH);
#pragma unroll
        for (int j = 0; j < 8; j++) acc[j] += w0 * bf2f(v[j]);
    }

    float* hp = h + (long long)node * HIDC + out_half * GCH + c8;
    f32x4 v0 = *(f32x4*)hp;
    f32x4 v1 = *(f32x4*)(hp + 4);
#pragma unroll
    for (int j = 0; j < 4; j++) {
        v0[j] += acc[j] + cb[c8 + j];
        v1[j] += acc[4 + j] + cb[c8 + 4 + j];
    }
    *(f32x4*)hp = v0;
    *(f32x4*)(hp + 4) = v1;
}

// ---- final: out = relu(LN256(h)) @ W2 + b2 (R5-proven) ----
#define FSTR 280
__global__ __launch_bounds__(256) void k_final(
    const float* __restrict__ h,
    const unsigned short* __restrict__ w2t,
    const float* __restrict__ fgf, const float* __restrict__ fbf,
    const float* __restrict__ b2f,
    const int* __restrict__ flags,
    void* __restrict__ out)
{
    __shared__ __align__(16) unsigned short a_tile[64 * FSTR];
    int t = threadIdx.x;
    int r0 = blockIdx.x * 64;

    int row = t >> 2, q = t & 3;
    int r = r0 + row;
    const float* hp = h + (long long)r * HIDC + q * 64;
    float sum = 0.f, sq = 0.f;
    float vbuf[64];
    if (r < NN) {
#pragma unroll
        for (int i = 0; i < 16; i++) {
            f32x4 v = *(const f32x4*)(hp + i * 4);
#pragma unroll
            for (int j = 0; j < 4; j++) {
                vbuf[i * 4 + j] = v[j];
                sum += v[j];
                sq += v[j] * v[j];
            }
        }
    } else {
#pragma unroll
        for (int i = 0; i < 64; i++) vbuf[i] = 0.f;
    }
    sum += __shfl_xor(sum, 1, 64);
    sum += __shfl_xor(sum, 2, 64);
    sq  += __shfl_xor(sq, 1, 64);
    sq  += __shfl_xor(sq, 2, 64);
    float mu = sum * (1.0f / HIDC);
    float var = sq * (1.0f / HIDC) - mu * mu;
    float rs = rsqrtf(var + EPSV);

#pragma unroll
    for (int i = 0; i < 16; i++) {
        int c = q * 64 + i * 4;
        u16x4 o;
#pragma unroll
        for (int j = 0; j < 4; j++) {
            float val = (vbuf[i * 4 + j] - mu) * rs * fgf[c + j] + fbf[c + j];
            if (val < 0.f) val = 0.f;
            o[j] = f2bf(val);
        }
        *(u16x4*)(&a_tile[row * FSTR + c]) = o;
    }
    __syncthreads();

    int w = t >> 6, lane = t & 63;
    int quad = lane >> 4, ln = lane & 15;
    const f32x4 zf = {0.f, 0.f, 0.f, 0.f};
    f32x4 acc[3];
#pragma unroll
    for (int j = 0; j < 3; j++) acc[j] = zf;
#pragma unroll
    for (int kk = 0; kk < 8; kk++) {
        int ko = kk * 32 + quad * 8;
        bf16x8 a = *(const bf16x8*)(&a_tile[(w * 16 + ln) * FSTR + ko]);
#pragma unroll
        for (int nf = 0; nf < 3; nf++) {
            bf16x8 b = ld8(w2t + (long long)(nf * 16 + ln) * HIDC + ko);
            acc[nf] = __builtin_amdgcn_mfma_f32_16x16x32_bf16(a, b, acc[nf], 0, 0, 0);
        }
    }
    int f32o = flags[1];
#pragma unroll
    for (int nf = 0; nf < 3; nf++) {
        int col = nf * 16 + ln;
        if (col >= OUTC) continue;
        float bias = b2f[col];
#pragma unroll
        for (int r4 = 0; r4 < 4; r4++) {
            int row2 = r0 + w * 16 + quad * 4 + r4;
            if (row2 < NN) {
                float val = acc[nf][r4] + bias;
                long long o = (long long)row2 * OUTC + col;
                if (f32o) ((float*)out)[o] = val;
                else      ((unsigned short*)out)[o] = f2bf(val);
            }
        }
    }
}

extern "C" void kernel_launch(void* const* d_in, const int* in_sizes, int n_in,
                              void* d_out, int out_size, void* d_ws, size_t ws_size,
                              hipStream_t stream)
{
    const void* x       = d_in[0];
    const int*  ei      = (const int*)d_in[1];
    const void* ew      = d_in[2];
    const void* lin1_w  = d_in[3];
    const void* lin1_b  = d_in[4];
    const void* lin2_w  = d_in[5];
    const void* lin2_b  = d_in[6];
    const void* norm_g  = d_in[7];
    const void* norm_b  = d_in[8];
    const void* conv_w  = d_in[9];
    const void* conv_b  = d_in[10];
    const void* fnorm_g = d_in[11];
    const void* fnorm_b = d_in[12];

    char* ws = (char*)d_ws;
    size_t off = 0;
    auto alloc = [&](size_t bytes) { void* p = (void*)(ws + off); off += (bytes + 255) & ~255ull; return p; };

    float*          h      = (float*)alloc((size_t)NN * HIDC * 4);
    unsigned short* z      = (unsigned short*)alloc((size_t)NN * GCH * 2);
    unsigned short* xb     = (unsigned short*)alloc((size_t)NN * INC * 2);
    unsigned short* w1t    = (unsigned short*)alloc((size_t)CVT_W1 * 2);
    unsigned short* cwt    = (unsigned short*)alloc((size_t)CVT_CW * 2);
    unsigned short* w2t    = (unsigned short*)alloc((size_t)CVT_W2 * 2);
    float*          b1f    = (float*)alloc(256 * 4);
    float*          ngf    = (float*)alloc(1024 * 4);
    float*          nbf    = (float*)alloc(1024 * 4);
    float*          cbf    = (float*)alloc(1024 * 4);
    float*          fgf    = (float*)alloc(256 * 4);
    float*          fbf    = (float*)alloc(256 * 4);
    float*          b2f    = (float*)alloc(48 * 4);
    int*            deg    = (int*)alloc((size_t)NN * 4);
    int*            rowptr = (int*)alloc(((size_t)NN + 1) * 4);
    int*            cursor = (int*)alloc((size_t)NN * 4);
    int*            ssrc   = (int*)alloc((size_t)NEDGE * 4);
    float*          sw     = (float*)alloc((size_t)NEDGE * 4);
    int*            flags  = (int*)alloc(256);
    int*            bsum   = (int*)alloc(SCAN_B * 4);
    int*            boff   = (int*)alloc(SCAN_B * 4);

    if (ws_size < off || n_in < 13) {
        float mv = 100.0f + (float)(ws_size >> 20) + ((n_in < 13) ? 10000.0f : 0.0f);
        k_marker<<<(out_size + 255) / 256, 256, 0, stream>>>(d_out, mv, out_size);
        return;
    }

    k_detect<<<196, 256, 0, stream>>>(ei, (const unsigned short*)x, flags, deg);
    k_convert<<<(CVT_TOT + 255) / 256, 256, 0, stream>>>(x, lin1_w, conv_w, lin2_w,
                                                         flags, xb, w1t, cwt, w2t);
    k_convert2<<<1, 256, 0, stream>>>(lin1_b, norm_g, norm_b, conv_b,
                                      fnorm_g, fnorm_b, lin2_b, flags,
                                      b1f, ngf, nbf, cbf, fgf, fbf, b2f);
    k_lin1<<<782, 256, 0, stream>>>(xb, w1t, b1f, h);

    k_count<<<(NEDGE / 2 + 255) / 256, 256, 0, stream>>>(ei, flags, deg);
    k_scan_a<<<SCAN_B, 256, 0, stream>>>(deg, bsum);
    k_scan_b<<<1, 64, 0, stream>>>(bsum, boff);
    k_scan_c<<<SCAN_B, 256, 0, stream>>>(deg, boff, rowptr, cursor);
    k_fill<<<(NEDGE / 2 + 255) / 256, 256, 0, stream>>>(ei, ew, flags, cursor, ssrc, sw);

    const int AGG_B = (NN + 15) / 16;   // 3125
    for (int l = 0; l < NL; l++) {
        for (int g = 0; g < NG; g++) {
            int lg = l * NG + g;
            int in_half = g ^ 1;
            k_ln_gemm<<<391, 256, 0, stream>>>(h, cwt + (size_t)lg * GCH * GCH,
                                               ngf + lg * GCH, nbf + lg * GCH,
                                               in_half, z);
            k_agg<<<AGG_B, 256, 0, stream>>>(rowptr, ssrc, sw, z,
                                             cbf + lg * GCH, h, g);
        }
    }
    k_final<<<782, 256, 0, stream>>>(h, w2t, fgf, fbf, b2f, flags, d_out);
}